// Round 11
// baseline (151.892 us; speedup 1.0000x reference)
//
#include <hip/hip_runtime.h>
#include <math.h>

#define NB 8192
#define NC 128
#define NSL 16         // j-slices (grid.y); slice = 512 cols
#define JPT 4          // j-tiles of 128 per slice

typedef float v4f __attribute__((ext_vector_type(4)));
typedef int   v8i __attribute__((ext_vector_type(8)));   // 32 fp8 (8 VGPRs)

// ---------------------------------------------------------------- prep:
// per row: fp8 e4m3 cast (packed 4/lane), sum-of-squares (fp32), CE term
// (fp32); zero sums/cnt. 8 rows per 256-thr block, 32 lanes per row.
__global__ __launch_bounds__(256) void k_prep(const float* __restrict__ x,
                                              const int* __restrict__ tgt,
                                              unsigned* __restrict__ xq,   // NB*32 uints (4 fp8 each)
                                              float* __restrict__ sq,
                                              float* __restrict__ ce,
                                              float* __restrict__ sums,
                                              unsigned* __restrict__ cnt) {
    int row = blockIdx.x * 8 + (threadIdx.x >> 5);
    int l = threadIdx.x & 31;
    float4 v = ((const float4*)(x + row * NC))[l];
    unsigned p = __builtin_amdgcn_cvt_pk_fp8_f32(v.x, v.y, 0, false);
    p = __builtin_amdgcn_cvt_pk_fp8_f32(v.z, v.w, p, true);
    xq[row * 32 + l] = p;

    float ss = fmaf(v.x, v.x, fmaf(v.y, v.y, fmaf(v.z, v.z, v.w * v.w)));
    float mx = fmaxf(fmaxf(v.x, v.y), fmaxf(v.z, v.w));
#pragma unroll
    for (int off = 16; off; off >>= 1) {        // offsets <32: stay within half-wave
        ss += __shfl_xor(ss, off);
        mx = fmaxf(mx, __shfl_xor(mx, off));
    }
    float es = expf(v.x - mx) + expf(v.y - mx) + expf(v.z - mx) + expf(v.w - mx);
#pragma unroll
    for (int off = 16; off; off >>= 1) es += __shfl_xor(es, off);
    if (l == 0) {
        sq[row] = ss;
        ce[row] = mx + logf(es) - x[row * NC + tgt[row]];
    }
    if (blockIdx.x == 0 && threadIdx.x < 4) {
        if (threadIdx.x < 2) sums[threadIdx.x] = 0.0f;
        if (threadIdx.x == 2) *cnt = 0u;
    }
}

// ---------------------------------------------------------------- triplet:
// SYMMETRIC triangular sweep: tile (ib, jtg) kept iff ib >= 2*jtg (50.8% of
// tiles); each kept tile is reduced BOTH row-wise (anchor = row) and
// col-wise (anchor = col). Coverage: for any pair (i,j), floor(i/64) >=
// 2*floor(j/128) or floor(j/64) >= 2*floor(i/128) (proof: both failing is
// contradictory). Values are bit-identical to the full sweep: fp8 dot is
// operand-order symmetric, fmaf forms match, fp32 max/min order-free.
// Row partials -> rmax/rmin[32][NB] at slice 2s+ch (disjoint rows per rh —
// no race). Col partials -> cmax/cmin[256][NB] at slice 2*(ib-2jtg)+rh:
// the rh SPLIT is the R10 race fix — each row-half wave owns its own
// slice (dense, exactly one writer, no init, no atomics).
__global__ __launch_bounds__(256, 4) void k_trip(const unsigned char* __restrict__ xq,
                                                 const int* __restrict__ tgt,
                                                 const float* __restrict__ sq,
                                                 float* __restrict__ rmax,   // [32][NB]
                                                 float* __restrict__ rmin,   // [32][NB]
                                                 float* __restrict__ cmax,   // [256][NB]
                                                 float* __restrict__ cmin) { // [256][NB]
    const int ib = blockIdx.x;
    const int s = blockIdx.y;
    if (ib < 8 * s) return;                       // no sub-diagonal tile here
    const int jtmax = min(3, (ib - 8 * s) >> 1);  // tile jt kept iff ib >= 8s+2jt

    __shared__ unsigned char Bs[2][128 * 128];  // 2 x 16 KB
    __shared__ float sqs[512];                  // 2 KB  (slice sq)
    __shared__ int   tjs[512];                  // 2 KB  (slice tgt)

    const int tid = threadIdx.x;
    const int lane = tid & 63;
    const int w = tid >> 6;           // wave 0..3
    const int rh = w >> 1;            // row half (32 rows)
    const int ch = w & 1;             // col half (64 cols)
    const int i0 = ib * 64;
    const int jbase = s * 512;
    const int m = lane & 15;
    const int quad = lane >> 4;

    // ---- slice metadata -> LDS (once; covered by first loop barrier) ----
    if (tid < 128) {
        float4 s4 = *(const float4*)(sq + jbase + tid * 4);
        int4 t4 = *(const int4*)(tgt + jbase + tid * 4);
        *(float4*)&sqs[tid * 4] = s4;
        *(int4*)&tjs[tid * 4] = t4;
    }

    // ---- stage B tile 0 into buffer 0 (async, source-side XOR swizzle) ----
#pragma unroll
    for (int c = 0; c < 4; ++c) {
        int L = w * 256 + c * 64 + lane;          // 16-B chunk index 0..1023
        int col = L >> 3, cc = L & 7;
        const unsigned char* src = xq + (size_t)(jbase + col) * 128 + ((cc ^ (col & 7)) << 4);
        __builtin_amdgcn_global_load_lds(
            (const __attribute__((address_space(1))) unsigned*)src,
            (__attribute__((address_space(3))) unsigned*)(&Bs[0][0] + (w * 256 + c * 64) * 16),
            16, 0, 0);
    }

    // ---- A fragments straight into registers (32 B/frag, once per block) ----
    v8i a[2];
#pragma unroll
    for (int tm = 0; tm < 2; ++tm) {
        int row = i0 + rh * 32 + tm * 16 + m;
        a[tm] = *(const v8i*)(xq + (size_t)row * 128 + quad * 32);
    }

    // ---- anchor targets + row sq for this lane's output rows ----
    int ti[2][4];
    float sqr[2][4];
#pragma unroll
    for (int tm = 0; tm < 2; ++tm)
#pragma unroll
        for (int r = 0; r < 4; ++r) {
            int row = i0 + rh * 32 + tm * 16 + quad * 4 + r;
            ti[tm][r] = tgt[row];
            sqr[tm][r] = sq[row];
        }

    float mp[2][4], mn[2][4];
#pragma unroll
    for (int tm = 0; tm < 2; ++tm)
#pragma unroll
        for (int r = 0; r < 4; ++r) { mp[tm][r] = -3.0e38f; mn[tm][r] = 3.0e38f; }

    for (int jt = 0; jt <= jtmax; ++jt) {
        // drains prefetch issued one full iteration ago; meta/A visible too
        __syncthreads();

        // ---- early-issue prefetch of NEXT kept B tile ----
        if (jt < jtmax) {
            int jn = jbase + (jt + 1) * 128;
            unsigned char* Bnxt = &Bs[(jt + 1) & 1][0];
#pragma unroll
            for (int c = 0; c < 4; ++c) {
                int L = w * 256 + c * 64 + lane;
                int col = L >> 3, cc = L & 7;
                const unsigned char* src = xq + (size_t)(jn + col) * 128 + ((cc ^ (col & 7)) << 4);
                __builtin_amdgcn_global_load_lds(
                    (const __attribute__((address_space(1))) unsigned*)src,
                    (__attribute__((address_space(3))) unsigned*)(Bnxt + (w * 256 + c * 64) * 16),
                    16, 0, 0);
            }
        }

        const unsigned char* Bcur = &Bs[jt & 1][0];
        const v4f z = {0.0f, 0.0f, 0.0f, 0.0f};

        float cmx[4], cmn[4];                 // col-side partials (this tile, this rh)
#pragma unroll
        for (int tn = 0; tn < 4; ++tn) { cmx[tn] = -3.0e38f; cmn[tn] = 3.0e38f; }

#pragma unroll
        for (int tn = 0; tn < 4; ++tn) {
            int cloc = ch * 64 + tn * 16 + m;
            float sqj = sqs[jt * 128 + cloc];
            int tj = tjs[jt * 128 + cloc];

            // ---- b fragment: two b128 reads (XOR-swizzled) ----
            v8i b;
            int base = cloc * 128;
            *(int4*)&b = *(const int4*)(Bcur + base + ((((quad * 2) ^ (cloc & 7))) << 4));
            *((int4*)&b + 1) = *(const int4*)(Bcur + base + ((((quad * 2 + 1) ^ (cloc & 7))) << 4));

            // ---- one MX MFMA per tm covers all K=128; scales = 1.0 ----
            v4f acc0 = __builtin_amdgcn_mfma_scale_f32_16x16x128_f8f6f4(
                a[0], b, z, 0, 0, 0, 0x7f7f7f7f, 0, 0x7f7f7f7f);
            v4f acc1 = __builtin_amdgcn_mfma_scale_f32_16x16x128_f8f6f4(
                a[1], b, z, 0, 0, 0, 0x7f7f7f7f, 0, 0x7f7f7f7f);

            // ---- dual epilogue: row-side (d2 = sqj - 2dot, tail adds sq_row)
            //      + col-side (vc = sq_row - 2dot, tail adds sq_col) ----
#pragma unroll
            for (int r = 0; r < 4; ++r) {
                {
                    float d2 = fmaf(-2.0f, acc0[r], sqj);
                    bool pos = (tj == ti[0][r]);
                    mp[0][r] = fmaxf(mp[0][r], pos ? d2 : -3.0e38f);
                    mn[0][r] = fminf(mn[0][r], pos ? 3.0e38f : d2);
                    float vc = fmaf(-2.0f, acc0[r], sqr[0][r]);
                    cmx[tn] = fmaxf(cmx[tn], pos ? vc : -3.0e38f);
                    cmn[tn] = fminf(cmn[tn], pos ? 3.0e38f : vc);
                }
                {
                    float d2 = fmaf(-2.0f, acc1[r], sqj);
                    bool pos = (tj == ti[1][r]);
                    mp[1][r] = fmaxf(mp[1][r], pos ? d2 : -3.0e38f);
                    mn[1][r] = fminf(mn[1][r], pos ? 3.0e38f : d2);
                    float vc = fmaf(-2.0f, acc1[r], sqr[1][r]);
                    cmx[tn] = fmaxf(cmx[tn], pos ? vc : -3.0e38f);
                    cmn[tn] = fminf(cmn[tn], pos ? 3.0e38f : vc);
                }
            }
        }

        // ---- col cross-lane reduce (over quad) & store to rh-private slice ----
#pragma unroll
        for (int tn = 0; tn < 4; ++tn) {
            float x1 = cmx[tn], n1 = cmn[tn];
            x1 = fmaxf(x1, __shfl_xor(x1, 16));
            x1 = fmaxf(x1, __shfl_xor(x1, 32));
            n1 = fminf(n1, __shfl_xor(n1, 16));
            n1 = fminf(n1, __shfl_xor(n1, 32));
            if (quad == 0) {
                int jcol = jbase + jt * 128 + ch * 64 + tn * 16 + m;
                int slice_c = (((ib - 8 * s - 2 * jt)) << 1) + rh;   // rh-split: no race
                cmax[(size_t)slice_c * NB + jcol] = x1;
                cmin[(size_t)slice_c * NB + jcol] = n1;
            }
        }
    }

    // ---- row-side: reduce across the 16 m-lanes sharing each output row ----
#pragma unroll
    for (int off = 1; off < 16; off <<= 1) {
#pragma unroll
        for (int tm = 0; tm < 2; ++tm)
#pragma unroll
            for (int r = 0; r < 4; ++r) {
                mp[tm][r] = fmaxf(mp[tm][r], __shfl_xor(mp[tm][r], off));
                mn[tm][r] = fminf(mn[tm][r], __shfl_xor(mn[tm][r], off));
            }
    }
    if (m == 0) {
        int slice = s * 2 + ch;
        float* pm = rmax + (size_t)slice * NB + i0 + rh * 32;
        float* pn = rmin + (size_t)slice * NB + i0 + rh * 32;
#pragma unroll
        for (int tm = 0; tm < 2; ++tm)
#pragma unroll
            for (int r = 0; r < 4; ++r) {
                int rr = tm * 16 + quad * 4 + r;
                pm[rr] = mp[tm][r];
                pn[rr] = mn[tm][r];
            }
    }
}

// ---------------------------------------------------------------- tail:
// combine row slices (stored sq_col - 2dot; add sq[i]) + col slices
// (stored sq_row - 2dot; add sq[i] = the col anchor's own sq), hinge,
// CE sum -> atomic partials; last block runs the Lambert-W scalar.
__global__ __launch_bounds__(256) void k_tail(const float* __restrict__ sq,
                                              const float* __restrict__ ce,
                                              const float* __restrict__ rmax,
                                              const float* __restrict__ rmin,
                                              const float* __restrict__ cmax,
                                              const float* __restrict__ cmin,
                                              float* __restrict__ sums,
                                              unsigned* __restrict__ cnt,
                                              float* __restrict__ out) {
    __shared__ float sh[4], sc[4];
    __shared__ unsigned lastFlag;
    const int tid = threadIdx.x;
    int i = blockIdx.x * 256 + tid;

    float vmax = -3.0e38f, vmin = 3.0e38f;
    int nrow = 2 * (i >> 9) + 2;                  // row slices: s <= ib/8
    for (int sl = 0; sl < nrow; ++sl) {
        vmax = fmaxf(vmax, rmax[(size_t)sl * NB + i]);
        vmin = fminf(vmin, rmin[(size_t)sl * NB + i]);
    }
    int ncol = (128 - 2 * (i >> 7)) << 1;         // col slices (rh-split, dense)
    for (int sl = 0; sl < ncol; ++sl) {
        vmax = fmaxf(vmax, cmax[(size_t)sl * NB + i]);
        vmin = fminf(vmin, cmin[(size_t)sl * NB + i]);
    }
    float sqi = sq[i];
    float ap = sqrtf(fmaxf(fmaxf(sqi + vmax, 0.0f), 1e-12f));
    float an = sqrtf(fmaxf(fmaxf(sqi + vmin, 0.0f), 1e-12f));
    float hs = fmaxf(ap - an + 0.3f, 0.0f);
    float cs = ce[i];
#pragma unroll
    for (int off = 32; off; off >>= 1) {
        hs += __shfl_xor(hs, off);
        cs += __shfl_xor(cs, off);
    }
    int wv = tid >> 6;
    if ((tid & 63) == 0) { sh[wv] = hs; sc[wv] = cs; }
    __syncthreads();
    if (tid == 0) {
        float H = sh[0] + sh[1] + sh[2] + sh[3];
        float Cs = sc[0] + sc[1] + sc[2] + sc[3];
        atomicAdd(sums + 0, H);
        atomicAdd(sums + 1, Cs);
        __threadfence();
        unsigned prev = atomicAdd(cnt, 1u);
        lastFlag = (prev == (unsigned)(gridDim.x - 1));
    }
    __syncthreads();
    if (!lastFlag || tid != 0) return;

    // last block, thread 0: scalar Lambert-W tail
    double H = (double)atomicAdd(sums + 0, 0.0f);
    double Cs = (double)atomicAdd(sums + 1, 0.0f);
    const double E = 2.71828182845904523536;
    const double TAU = log(128.0);
    const double LAMd = 0.25;
    double l = H / (double)NB;
    double cev = Cs / (double)NB;
    double y = 0.5 * fmax(-2.0 / E, (l - TAU) / LAMd);
    double p = sqrt(fmax(2.0 * (E * y + 1.0), 0.0));
    double wn = -1.0 + p - p * p / 3.0 + (11.0 / 72.0) * p * p * p;
    double wlw = (y < 0.0) ? wn : log1p(fmax(y, 0.0));
#pragma unroll
    for (int it = 0; it < 10; ++it) {
        double ew = exp(wlw);
        double f = wlw * ew - y;
        double wp1 = wlw + 1.0;
        wlw = wlw - f / (ew * wp1 - (wlw + 2.0) * f / (2.0 * wp1));
    }
    double sigma = exp(-wlw);
    double lg = log(sigma);
    double loss = (cev - TAU) * sigma + LAMd * lg * lg;
    out[0] = (float)(loss / (double)NB);
}

// ---------------------------------------------------------------- launcher
extern "C" void kernel_launch(void* const* d_in, const int* in_sizes, int n_in,
                              void* d_out, int out_size, void* d_ws, size_t ws_size,
                              hipStream_t stream) {
    const float* x = (const float*)d_in[0];
    const int* tgt = (const int*)d_in[1];
    float* out = (float*)d_out;

    // ws: xq 1MB | sq | ce | sums/cnt | rmax 1MB | rmin 1MB | cmax 8MB | cmin 8MB
    unsigned char* xq = (unsigned char*)d_ws;
    float* sq = (float*)(xq + (size_t)NB * 128);
    float* ce = sq + NB;
    float* sums = ce + NB;
    unsigned* cnt = (unsigned*)(sums + 2);
    float* rmax = (float*)(cnt + 62);              // 256-B aligned
    float* rmin = rmax + (size_t)32 * NB;
    float* cmax = rmin + (size_t)32 * NB;
    float* cmin = cmax + (size_t)256 * NB;

    k_prep<<<NB / 8, 256, 0, stream>>>(x, tgt, (unsigned*)xq, sq, ce, sums, cnt);
    dim3 grid(NB / 64, NSL);
    k_trip<<<grid, 256, 0, stream>>>(xq, tgt, sq, rmax, rmin, cmax, cmin);
    k_tail<<<NB / 256, 256, 0, stream>>>(sq, ce, rmax, rmin, cmax, cmin, sums, cnt, out);
}

// Round 12
// 101.841 us; speedup vs baseline: 1.4915x; 1.4915x over previous
//
#include <hip/hip_runtime.h>
#include <math.h>

#define NB 8192
#define NC 128
#define NSL 16         // j-slices (grid.y); slice = 512 cols
#define JPT 4          // j-tiles of 128 per slice

typedef float v4f __attribute__((ext_vector_type(4)));
typedef int   v8i __attribute__((ext_vector_type(8)));   // 32 fp8 (8 VGPRs)

// ---------------------------------------------------------------- prep:
// per row: fp8 e4m3 cast (packed 4/lane), sum-of-squares (fp32), CE term
// (fp32); zero sums/cnt. 8 rows per 256-thr block, 32 lanes per row.
__global__ __launch_bounds__(256) void k_prep(const float* __restrict__ x,
                                              const int* __restrict__ tgt,
                                              unsigned* __restrict__ xq,   // NB*32 uints (4 fp8 each)
                                              float* __restrict__ sq,
                                              float* __restrict__ ce,
                                              float* __restrict__ sums,
                                              unsigned* __restrict__ cnt) {
    int row = blockIdx.x * 8 + (threadIdx.x >> 5);
    int l = threadIdx.x & 31;
    float4 v = ((const float4*)(x + row * NC))[l];
    unsigned p = __builtin_amdgcn_cvt_pk_fp8_f32(v.x, v.y, 0, false);
    p = __builtin_amdgcn_cvt_pk_fp8_f32(v.z, v.w, p, true);
    xq[row * 32 + l] = p;

    float ss = fmaf(v.x, v.x, fmaf(v.y, v.y, fmaf(v.z, v.z, v.w * v.w)));
    float mx = fmaxf(fmaxf(v.x, v.y), fmaxf(v.z, v.w));
#pragma unroll
    for (int off = 16; off; off >>= 1) {        // offsets <32: stay within half-wave
        ss += __shfl_xor(ss, off);
        mx = fmaxf(mx, __shfl_xor(mx, off));
    }
    float es = expf(v.x - mx) + expf(v.y - mx) + expf(v.z - mx) + expf(v.w - mx);
#pragma unroll
    for (int off = 16; off; off >>= 1) es += __shfl_xor(es, off);
    if (l == 0) {
        sq[row] = ss;
        ce[row] = mx + logf(es) - x[row * NC + tgt[row]];
    }
    if (blockIdx.x == 0 && threadIdx.x < 4) {
        if (threadIdx.x < 2) sums[threadIdx.x] = 0.0f;
        if (threadIdx.x == 2) *cnt = 0u;
    }
}

// ---------------------------------------------------------------- triplet:
// SYMMETRIC triangular sweep: tile (ib, jtg) kept iff ib >= 2*jtg (50.8% of
// tiles); each kept tile is reduced BOTH row-wise (anchor = row) and
// col-wise (anchor = col). Coverage: for any pair (i,j), floor(i/64) >=
// 2*floor(j/128) or floor(j/64) >= 2*floor(i/128). Values bit-identical
// to the full sweep (fp8 dot symmetric; fp32 max/min order-free).
// Row partials -> rmax/rmin[32][NB] at slice 2s+ch. Col partials ->
// cmax/cmin[256][NB] at slice 2*(ib-2jtg)+rh (rh split = R10 race fix;
// dense, exactly one writer, no init, no atomics). UNCHANGED from R11
// (verified absmax 0.0).
__global__ __launch_bounds__(256, 4) void k_trip(const unsigned char* __restrict__ xq,
                                                 const int* __restrict__ tgt,
                                                 const float* __restrict__ sq,
                                                 float* __restrict__ rmax,   // [32][NB]
                                                 float* __restrict__ rmin,   // [32][NB]
                                                 float* __restrict__ cmax,   // [256][NB]
                                                 float* __restrict__ cmin) { // [256][NB]
    const int ib = blockIdx.x;
    const int s = blockIdx.y;
    if (ib < 8 * s) return;                       // no sub-diagonal tile here
    const int jtmax = min(3, (ib - 8 * s) >> 1);  // tile jt kept iff ib >= 8s+2jt

    __shared__ unsigned char Bs[2][128 * 128];  // 2 x 16 KB
    __shared__ float sqs[512];                  // 2 KB  (slice sq)
    __shared__ int   tjs[512];                  // 2 KB  (slice tgt)

    const int tid = threadIdx.x;
    const int lane = tid & 63;
    const int w = tid >> 6;           // wave 0..3
    const int rh = w >> 1;            // row half (32 rows)
    const int ch = w & 1;             // col half (64 cols)
    const int i0 = ib * 64;
    const int jbase = s * 512;
    const int m = lane & 15;
    const int quad = lane >> 4;

    // ---- slice metadata -> LDS (once; covered by first loop barrier) ----
    if (tid < 128) {
        float4 s4 = *(const float4*)(sq + jbase + tid * 4);
        int4 t4 = *(const int4*)(tgt + jbase + tid * 4);
        *(float4*)&sqs[tid * 4] = s4;
        *(int4*)&tjs[tid * 4] = t4;
    }

    // ---- stage B tile 0 into buffer 0 (async, source-side XOR swizzle) ----
#pragma unroll
    for (int c = 0; c < 4; ++c) {
        int L = w * 256 + c * 64 + lane;          // 16-B chunk index 0..1023
        int col = L >> 3, cc = L & 7;
        const unsigned char* src = xq + (size_t)(jbase + col) * 128 + ((cc ^ (col & 7)) << 4);
        __builtin_amdgcn_global_load_lds(
            (const __attribute__((address_space(1))) unsigned*)src,
            (__attribute__((address_space(3))) unsigned*)(&Bs[0][0] + (w * 256 + c * 64) * 16),
            16, 0, 0);
    }

    // ---- A fragments straight into registers (32 B/frag, once per block) ----
    v8i a[2];
#pragma unroll
    for (int tm = 0; tm < 2; ++tm) {
        int row = i0 + rh * 32 + tm * 16 + m;
        a[tm] = *(const v8i*)(xq + (size_t)row * 128 + quad * 32);
    }

    // ---- anchor targets + row sq for this lane's output rows ----
    int ti[2][4];
    float sqr[2][4];
#pragma unroll
    for (int tm = 0; tm < 2; ++tm)
#pragma unroll
        for (int r = 0; r < 4; ++r) {
            int row = i0 + rh * 32 + tm * 16 + quad * 4 + r;
            ti[tm][r] = tgt[row];
            sqr[tm][r] = sq[row];
        }

    float mp[2][4], mn[2][4];
#pragma unroll
    for (int tm = 0; tm < 2; ++tm)
#pragma unroll
        for (int r = 0; r < 4; ++r) { mp[tm][r] = -3.0e38f; mn[tm][r] = 3.0e38f; }

    for (int jt = 0; jt <= jtmax; ++jt) {
        // drains prefetch issued one full iteration ago; meta/A visible too
        __syncthreads();

        // ---- early-issue prefetch of NEXT kept B tile ----
        if (jt < jtmax) {
            int jn = jbase + (jt + 1) * 128;
            unsigned char* Bnxt = &Bs[(jt + 1) & 1][0];
#pragma unroll
            for (int c = 0; c < 4; ++c) {
                int L = w * 256 + c * 64 + lane;
                int col = L >> 3, cc = L & 7;
                const unsigned char* src = xq + (size_t)(jn + col) * 128 + ((cc ^ (col & 7)) << 4);
                __builtin_amdgcn_global_load_lds(
                    (const __attribute__((address_space(1))) unsigned*)src,
                    (__attribute__((address_space(3))) unsigned*)(Bnxt + (w * 256 + c * 64) * 16),
                    16, 0, 0);
            }
        }

        const unsigned char* Bcur = &Bs[jt & 1][0];
        const v4f z = {0.0f, 0.0f, 0.0f, 0.0f};

        float cmx[4], cmn[4];                 // col-side partials (this tile, this rh)
#pragma unroll
        for (int tn = 0; tn < 4; ++tn) { cmx[tn] = -3.0e38f; cmn[tn] = 3.0e38f; }

#pragma unroll
        for (int tn = 0; tn < 4; ++tn) {
            int cloc = ch * 64 + tn * 16 + m;
            float sqj = sqs[jt * 128 + cloc];
            int tj = tjs[jt * 128 + cloc];

            // ---- b fragment: two b128 reads (XOR-swizzled) ----
            v8i b;
            int base = cloc * 128;
            *(int4*)&b = *(const int4*)(Bcur + base + ((((quad * 2) ^ (cloc & 7))) << 4));
            *((int4*)&b + 1) = *(const int4*)(Bcur + base + ((((quad * 2 + 1) ^ (cloc & 7))) << 4));

            // ---- one MX MFMA per tm covers all K=128; scales = 1.0 ----
            v4f acc0 = __builtin_amdgcn_mfma_scale_f32_16x16x128_f8f6f4(
                a[0], b, z, 0, 0, 0, 0x7f7f7f7f, 0, 0x7f7f7f7f);
            v4f acc1 = __builtin_amdgcn_mfma_scale_f32_16x16x128_f8f6f4(
                a[1], b, z, 0, 0, 0, 0x7f7f7f7f, 0, 0x7f7f7f7f);

            // ---- dual epilogue: row-side (d2 = sqj - 2dot, tail adds sq_row)
            //      + col-side (vc = sq_row - 2dot, tail adds sq_col) ----
#pragma unroll
            for (int r = 0; r < 4; ++r) {
                {
                    float d2 = fmaf(-2.0f, acc0[r], sqj);
                    bool pos = (tj == ti[0][r]);
                    mp[0][r] = fmaxf(mp[0][r], pos ? d2 : -3.0e38f);
                    mn[0][r] = fminf(mn[0][r], pos ? 3.0e38f : d2);
                    float vc = fmaf(-2.0f, acc0[r], sqr[0][r]);
                    cmx[tn] = fmaxf(cmx[tn], pos ? vc : -3.0e38f);
                    cmn[tn] = fminf(cmn[tn], pos ? 3.0e38f : vc);
                }
                {
                    float d2 = fmaf(-2.0f, acc1[r], sqj);
                    bool pos = (tj == ti[1][r]);
                    mp[1][r] = fmaxf(mp[1][r], pos ? d2 : -3.0e38f);
                    mn[1][r] = fminf(mn[1][r], pos ? 3.0e38f : d2);
                    float vc = fmaf(-2.0f, acc1[r], sqr[1][r]);
                    cmx[tn] = fmaxf(cmx[tn], pos ? vc : -3.0e38f);
                    cmn[tn] = fminf(cmn[tn], pos ? 3.0e38f : vc);
                }
            }
        }

        // ---- col cross-lane reduce (over quad) & store to rh-private slice ----
#pragma unroll
        for (int tn = 0; tn < 4; ++tn) {
            float x1 = cmx[tn], n1 = cmn[tn];
            x1 = fmaxf(x1, __shfl_xor(x1, 16));
            x1 = fmaxf(x1, __shfl_xor(x1, 32));
            n1 = fminf(n1, __shfl_xor(n1, 16));
            n1 = fminf(n1, __shfl_xor(n1, 32));
            if (quad == 0) {
                int jcol = jbase + jt * 128 + ch * 64 + tn * 16 + m;
                int slice_c = (((ib - 8 * s - 2 * jt)) << 1) + rh;   // rh-split: no race
                cmax[(size_t)slice_c * NB + jcol] = x1;
                cmin[(size_t)slice_c * NB + jcol] = n1;
            }
        }
    }

    // ---- row-side: reduce across the 16 m-lanes sharing each output row ----
#pragma unroll
    for (int off = 1; off < 16; off <<= 1) {
#pragma unroll
        for (int tm = 0; tm < 2; ++tm)
#pragma unroll
            for (int r = 0; r < 4; ++r) {
                mp[tm][r] = fmaxf(mp[tm][r], __shfl_xor(mp[tm][r], off));
                mn[tm][r] = fminf(mn[tm][r], __shfl_xor(mn[tm][r], off));
            }
    }
    if (m == 0) {
        int slice = s * 2 + ch;
        float* pm = rmax + (size_t)slice * NB + i0 + rh * 32;
        float* pn = rmin + (size_t)slice * NB + i0 + rh * 32;
#pragma unroll
        for (int tm = 0; tm < 2; ++tm)
#pragma unroll
            for (int r = 0; r < 4; ++r) {
                int rr = tm * 16 + quad * 4 + r;
                pm[rr] = mp[tm][r];
                pn[rr] = mn[tm][r];
            }
    }
}

// ---------------------------------------------------------------- tail:
// PARALLEL slice combine: 256 blocks x 256 threads; thread (g=tid>>5,
// a=tid&31) covers anchor i = bx*32+a, slices strided by g over 8 groups
// (per-thread trip ~36 instead of ~260; for fixed slice the 32 a-lanes
// read 128 B contiguous). LDS [8][32] combine, first 32 lanes do
// hinge+CE, 2 atomics/block; last block runs the Lambert-W scalar.
__global__ __launch_bounds__(256) void k_tail(const float* __restrict__ sq,
                                              const float* __restrict__ ce,
                                              const float* __restrict__ rmax,
                                              const float* __restrict__ rmin,
                                              const float* __restrict__ cmax,
                                              const float* __restrict__ cmin,
                                              float* __restrict__ sums,
                                              unsigned* __restrict__ cnt,
                                              float* __restrict__ out) {
    __shared__ float smax[8][32], smin[8][32];
    __shared__ unsigned lastFlag;
    const int tid = threadIdx.x;
    const int a = tid & 31, g = tid >> 5;
    const int i = blockIdx.x * 32 + a;

    float vmax = -3.0e38f, vmin = 3.0e38f;
    int nrow = 2 * (i >> 9) + 2;                  // row slices: s <= ib/8
    for (int sl = g; sl < nrow; sl += 8) {
        vmax = fmaxf(vmax, rmax[(size_t)sl * NB + i]);
        vmin = fminf(vmin, rmin[(size_t)sl * NB + i]);
    }
    int ncol = (128 - 2 * (i >> 7)) << 1;         // col slices (rh-split, dense)
    for (int sl = g; sl < ncol; sl += 8) {
        vmax = fmaxf(vmax, cmax[(size_t)sl * NB + i]);
        vmin = fminf(vmin, cmin[(size_t)sl * NB + i]);
    }
    smax[g][a] = vmax;
    smin[g][a] = vmin;
    __syncthreads();

    float hs = 0.0f, cs = 0.0f;
    if (tid < 32) {
        float vx = smax[0][tid], vn = smin[0][tid];
#pragma unroll
        for (int k = 1; k < 8; ++k) {
            vx = fmaxf(vx, smax[k][tid]);
            vn = fminf(vn, smin[k][tid]);
        }
        int ii = blockIdx.x * 32 + tid;
        float sqi = sq[ii];
        float ap = sqrtf(fmaxf(fmaxf(sqi + vx, 0.0f), 1e-12f));
        float an = sqrtf(fmaxf(fmaxf(sqi + vn, 0.0f), 1e-12f));
        hs = fmaxf(ap - an + 0.3f, 0.0f);
        cs = ce[ii];
    }
#pragma unroll
    for (int off = 16; off; off >>= 1) {          // lanes 0..31 of wave 0
        hs += __shfl_xor(hs, off);
        cs += __shfl_xor(cs, off);
    }
    if (tid == 0) {
        atomicAdd(sums + 0, hs);
        atomicAdd(sums + 1, cs);
        __threadfence();
        unsigned prev = atomicAdd(cnt, 1u);
        lastFlag = (prev == (unsigned)(gridDim.x - 1));
    }
    __syncthreads();
    if (!lastFlag || tid != 0) return;

    // last block, thread 0: scalar Lambert-W tail
    double H = (double)atomicAdd(sums + 0, 0.0f);
    double Cs = (double)atomicAdd(sums + 1, 0.0f);
    const double E = 2.71828182845904523536;
    const double TAU = log(128.0);
    const double LAMd = 0.25;
    double l = H / (double)NB;
    double cev = Cs / (double)NB;
    double y = 0.5 * fmax(-2.0 / E, (l - TAU) / LAMd);
    double p = sqrt(fmax(2.0 * (E * y + 1.0), 0.0));
    double wn = -1.0 + p - p * p / 3.0 + (11.0 / 72.0) * p * p * p;
    double wlw = (y < 0.0) ? wn : log1p(fmax(y, 0.0));
#pragma unroll
    for (int it = 0; it < 10; ++it) {
        double ew = exp(wlw);
        double f = wlw * ew - y;
        double wp1 = wlw + 1.0;
        wlw = wlw - f / (ew * wp1 - (wlw + 2.0) * f / (2.0 * wp1));
    }
    double sigma = exp(-wlw);
    double lg = log(sigma);
    double loss = (cev - TAU) * sigma + LAMd * lg * lg;
    out[0] = (float)(loss / (double)NB);
}

// ---------------------------------------------------------------- launcher
extern "C" void kernel_launch(void* const* d_in, const int* in_sizes, int n_in,
                              void* d_out, int out_size, void* d_ws, size_t ws_size,
                              hipStream_t stream) {
    const float* x = (const float*)d_in[0];
    const int* tgt = (const int*)d_in[1];
    float* out = (float*)d_out;

    // ws: xq 1MB | sq | ce | sums/cnt | rmax 1MB | rmin 1MB | cmax 8MB | cmin 8MB
    unsigned char* xq = (unsigned char*)d_ws;
    float* sq = (float*)(xq + (size_t)NB * 128);
    float* ce = sq + NB;
    float* sums = ce + NB;
    unsigned* cnt = (unsigned*)(sums + 2);
    float* rmax = (float*)(cnt + 62);              // 256-B aligned
    float* rmin = rmax + (size_t)32 * NB;
    float* cmax = rmin + (size_t)32 * NB;
    float* cmin = cmax + (size_t)256 * NB;

    k_prep<<<NB / 8, 256, 0, stream>>>(x, tgt, (unsigned*)xq, sq, ce, sums, cnt);
    dim3 grid(NB / 64, NSL);
    k_trip<<<grid, 256, 0, stream>>>(xq, tgt, sq, rmax, rmin, cmax, cmin);
    k_tail<<<NB / 32, 256, 0, stream>>>(sq, ce, rmax, rmin, cmax, cmin, sums, cnt, out);
}

// Round 13
// 100.510 us; speedup vs baseline: 1.5112x; 1.0132x over previous
//
#include <hip/hip_runtime.h>
#include <math.h>

#define NB 8192
#define NC 128
#define NJS 8          // j-slices (grid.y); slice = 1024 cols
#define JPT 8          // j-tiles of 128 per slice

typedef float v4f __attribute__((ext_vector_type(4)));
typedef int   v8i __attribute__((ext_vector_type(8)));   // 32 fp8 (8 VGPRs)

// ---------------------------------------------------------------- prep:
// per row: fp8 e4m3 cast (packed 4/lane), sum-of-squares (fp32), CE term
// (fp32); zero sums/cnt. 8 rows per 256-thr block, 32 lanes per row.
__global__ __launch_bounds__(256) void k_prep(const float* __restrict__ x,
                                              const int* __restrict__ tgt,
                                              unsigned* __restrict__ xq,   // NB*32 uints (4 fp8 each)
                                              float* __restrict__ sq,
                                              float* __restrict__ ce,
                                              float* __restrict__ sums,
                                              unsigned* __restrict__ cnt) {
    int row = blockIdx.x * 8 + (threadIdx.x >> 5);
    int l = threadIdx.x & 31;
    float4 v = ((const float4*)(x + row * NC))[l];
    unsigned p = __builtin_amdgcn_cvt_pk_fp8_f32(v.x, v.y, 0, false);
    p = __builtin_amdgcn_cvt_pk_fp8_f32(v.z, v.w, p, true);
    xq[row * 32 + l] = p;

    float ss = fmaf(v.x, v.x, fmaf(v.y, v.y, fmaf(v.z, v.z, v.w * v.w)));
    float mx = fmaxf(fmaxf(v.x, v.y), fmaxf(v.z, v.w));
#pragma unroll
    for (int off = 16; off; off >>= 1) {        // offsets <32: stay within half-wave
        ss += __shfl_xor(ss, off);
        mx = fmaxf(mx, __shfl_xor(mx, off));
    }
    float es = expf(v.x - mx) + expf(v.y - mx) + expf(v.z - mx) + expf(v.w - mx);
#pragma unroll
    for (int off = 16; off; off >>= 1) es += __shfl_xor(es, off);
    if (l == 0) {
        sq[row] = ss;
        ce[row] = mx + logf(es) - x[row * NC + tgt[row]];
    }
    if (blockIdx.x == 0 && threadIdx.x < 4) {
        if (threadIdx.x < 2) sums[threadIdx.x] = 0.0f;
        if (threadIdx.x == 2) *cnt = 0u;
    }
}

// ---------------------------------------------------------------- triplet:
// FP8 MX MFMA (16x16x128, unit scales), FULL sweep (R9 structure) with the
// LDS/barrier machinery REMOVED: B fragments are read directly from global
// — per wave per tile the B frag is a contiguous 2 KB of xq (lane(m,quad)
// reads bytes m*128 + quad*32: perfectly coalescible; B slice = 64 KB,
// L2-resident), so staging bought nothing but 9 barriers + vmcnt drains.
// No __shared__ at all -> waves stream independently; compiler pipelines
// loads across the fully-unrolled 8-tile loop via vmcnt. Per-tn epilogue
// keeps VGPR ~90 (<128 cap, 4 blocks/CU). Results bit-identical to R9.
__global__ __launch_bounds__(256, 4) void k_trip(const unsigned char* __restrict__ xq,
                                                 const int* __restrict__ tgt,
                                                 const float* __restrict__ sq,
                                                 float* __restrict__ pmax,   // [16][NB]
                                                 float* __restrict__ pmin) { // [16][NB]
    const int tid = threadIdx.x;
    const int lane = tid & 63;
    const int w = tid >> 6;           // wave 0..3
    const int rh = w >> 1;            // row half (32 rows)
    const int ch = w & 1;             // col half (64 cols)
    const int i0 = blockIdx.x * 64;
    const int jbase = blockIdx.y * 1024;
    const int m = lane & 15;
    const int quad = lane >> 4;

    // ---- A fragments straight into registers (32 B/frag, once per block) ----
    v8i a[2];
#pragma unroll
    for (int tm = 0; tm < 2; ++tm) {
        int row = i0 + rh * 32 + tm * 16 + m;
        a[tm] = *(const v8i*)(xq + (size_t)row * 128 + quad * 32);
    }

    // ---- anchor targets for this lane's output rows ----
    int ti[2][4];
#pragma unroll
    for (int tm = 0; tm < 2; ++tm)
#pragma unroll
        for (int r = 0; r < 4; ++r)
            ti[tm][r] = tgt[i0 + rh * 32 + tm * 16 + quad * 4 + r];

    float mp[2][4], mn[2][4];
#pragma unroll
    for (int tm = 0; tm < 2; ++tm)
#pragma unroll
        for (int r = 0; r < 4; ++r) { mp[tm][r] = -3.0e38f; mn[tm][r] = 3.0e38f; }

    const v4f z = {0.0f, 0.0f, 0.0f, 0.0f};

#pragma unroll
    for (int jt = 0; jt < JPT; ++jt) {
        int j0 = jbase + jt * 128;
#pragma unroll
        for (int tn = 0; tn < 4; ++tn) {
            int col = j0 + ch * 64 + tn * 16 + m;

            // B fragment direct from global (2x dwordx4, coalesced 2 KB/wave)
            v8i b = *(const v8i*)(xq + (size_t)col * 128 + quad * 32);
            float sqj = sq[col];
            int tj = tgt[col];

            // one MX MFMA per tm covers all K=128; scales = 1.0
            v4f acc0 = __builtin_amdgcn_mfma_scale_f32_16x16x128_f8f6f4(
                a[0], b, z, 0, 0, 0, 0x7f7f7f7f, 0, 0x7f7f7f7f);
            v4f acc1 = __builtin_amdgcn_mfma_scale_f32_16x16x128_f8f6f4(
                a[1], b, z, 0, 0, 0, 0x7f7f7f7f, 0, 0x7f7f7f7f);

            // fused epilogue: v = sqj - 2*dot (sqi added in k_tail)
#pragma unroll
            for (int r = 0; r < 4; ++r) {
                {
                    float v = fmaf(-2.0f, acc0[r], sqj);
                    bool pos = (tj == ti[0][r]);
                    mp[0][r] = fmaxf(mp[0][r], pos ? v : -3.0e38f);
                    mn[0][r] = fminf(mn[0][r], pos ? 3.0e38f : v);
                }
                {
                    float v = fmaf(-2.0f, acc1[r], sqj);
                    bool pos = (tj == ti[1][r]);
                    mp[1][r] = fmaxf(mp[1][r], pos ? v : -3.0e38f);
                    mn[1][r] = fminf(mn[1][r], pos ? 3.0e38f : v);
                }
            }
        }
    }

    // ---- reduce across the 16 m-lanes sharing each output row ----
#pragma unroll
    for (int off = 1; off < 16; off <<= 1) {
#pragma unroll
        for (int tm = 0; tm < 2; ++tm)
#pragma unroll
            for (int r = 0; r < 4; ++r) {
                mp[tm][r] = fmaxf(mp[tm][r], __shfl_xor(mp[tm][r], off));
                mn[tm][r] = fminf(mn[tm][r], __shfl_xor(mn[tm][r], off));
            }
    }
    // ---- plain stores to this wave's private (slice, row-range) ----
    if (m == 0) {
        int slice = blockIdx.y * 2 + ch;
        float* pm = pmax + (size_t)slice * NB + i0 + rh * 32;
        float* pn = pmin + (size_t)slice * NB + i0 + rh * 32;
#pragma unroll
        for (int tm = 0; tm < 2; ++tm)
#pragma unroll
            for (int r = 0; r < 4; ++r) {
                int rr = tm * 16 + quad * 4 + r;
                pm[rr] = mp[tm][r];
                pn[rr] = mn[tm][r];
            }
    }
}

// ---------------------------------------------------------------- tail:
// combine 16 slices (coalesced, fixed unroll), hinge, CE sum -> atomic
// partials; last block runs the Lambert-W scalar. (R9 structure.)
__global__ __launch_bounds__(256) void k_tail(const float* __restrict__ sq,
                                              const float* __restrict__ ce,
                                              const float* __restrict__ pmax,
                                              const float* __restrict__ pmin,
                                              float* __restrict__ sums,
                                              unsigned* __restrict__ cnt,
                                              float* __restrict__ out) {
    __shared__ float sh[4], sc[4];
    __shared__ unsigned lastFlag;
    const int tid = threadIdx.x;
    int i = blockIdx.x * 256 + tid;

    float vmax = -3.0e38f, vmin = 3.0e38f;
#pragma unroll
    for (int s = 0; s < 16; ++s) {
        vmax = fmaxf(vmax, pmax[s * NB + i]);
        vmin = fminf(vmin, pmin[s * NB + i]);
    }
    float sqi = sq[i];
    float ap = sqrtf(fmaxf(fmaxf(sqi + vmax, 0.0f), 1e-12f));
    float an = sqrtf(fmaxf(fmaxf(sqi + vmin, 0.0f), 1e-12f));
    float hs = fmaxf(ap - an + 0.3f, 0.0f);
    float cs = ce[i];
#pragma unroll
    for (int off = 32; off; off >>= 1) {
        hs += __shfl_xor(hs, off);
        cs += __shfl_xor(cs, off);
    }
    int wv = tid >> 6;
    if ((tid & 63) == 0) { sh[wv] = hs; sc[wv] = cs; }
    __syncthreads();
    if (tid == 0) {
        float H = sh[0] + sh[1] + sh[2] + sh[3];
        float Cs = sc[0] + sc[1] + sc[2] + sc[3];
        atomicAdd(sums + 0, H);
        atomicAdd(sums + 1, Cs);
        __threadfence();
        unsigned prev = atomicAdd(cnt, 1u);
        lastFlag = (prev == (unsigned)(gridDim.x - 1));
    }
    __syncthreads();
    if (!lastFlag || tid != 0) return;

    // last block, thread 0: scalar Lambert-W tail
    double H = (double)atomicAdd(sums + 0, 0.0f);
    double Cs = (double)atomicAdd(sums + 1, 0.0f);
    const double E = 2.71828182845904523536;
    const double TAU = log(128.0);
    const double LAMd = 0.25;
    double l = H / (double)NB;
    double cev = Cs / (double)NB;
    double y = 0.5 * fmax(-2.0 / E, (l - TAU) / LAMd);
    double p = sqrt(fmax(2.0 * (E * y + 1.0), 0.0));
    double wn = -1.0 + p - p * p / 3.0 + (11.0 / 72.0) * p * p * p;
    double wlw = (y < 0.0) ? wn : log1p(fmax(y, 0.0));
#pragma unroll
    for (int it = 0; it < 10; ++it) {
        double ew = exp(wlw);
        double f = wlw * ew - y;
        double wp1 = wlw + 1.0;
        wlw = wlw - f / (ew * wp1 - (wlw + 2.0) * f / (2.0 * wp1));
    }
    double sigma = exp(-wlw);
    double lg = log(sigma);
    double loss = (cev - TAU) * sigma + LAMd * lg * lg;
    out[0] = (float)(loss / (double)NB);
}

// ---------------------------------------------------------------- launcher
extern "C" void kernel_launch(void* const* d_in, const int* in_sizes, int n_in,
                              void* d_out, int out_size, void* d_ws, size_t ws_size,
                              hipStream_t stream) {
    const float* x = (const float*)d_in[0];
    const int* tgt = (const int*)d_in[1];
    float* out = (float*)d_out;

    // ws: xq (NB*128 B = 1 MB) | sq | ce | sums[2] | cnt | pad | pmax | pmin
    unsigned char* xq = (unsigned char*)d_ws;
    float* sq = (float*)(xq + (size_t)NB * 128);
    float* ce = sq + NB;
    float* sums = ce + NB;
    unsigned* cnt = (unsigned*)(sums + 2);
    float* pmax = (float*)(cnt + 62);              // keep 256-B alignment
    float* pmin = pmax + (size_t)16 * NB;

    k_prep<<<NB / 8, 256, 0, stream>>>(x, tgt, (unsigned*)xq, sq, ce, sums, cnt);
    dim3 grid(NB / 64, NJS);
    k_trip<<<grid, 256, 0, stream>>>(xq, tgt, sq, pmax, pmin);
    k_tail<<<NB / 256, 256, 0, stream>>>(sq, ce, pmax, pmin, sums, cnt, out);
}